// Round 3
// baseline (621.445 us; speedup 1.0000x reference)
//
#include <hip/hip_runtime.h>
#include <cstdint>

typedef uint32_t u32;
typedef __attribute__((ext_vector_type(4))) float f32x4;
typedef __attribute__((ext_vector_type(4))) u32   u32x4;
typedef __attribute__((ext_vector_type(8))) short bf16x8;

#define EDGES_PER_WG 16

// ---- bf16 RNE split for W prep (runs once, accuracy-first) ----
__device__ __forceinline__ u32 bf16_rne(float x) {
  u32 u = __builtin_bit_cast(u32, x);
  return (u + 0x7FFFu + ((u >> 16) & 1u)) >> 16;
}
__device__ __forceinline__ void split2(float x, u32 &h, u32 &l) {
  h = bf16_rne(x);
  float hf = __builtin_bit_cast(float, h << 16);
  l = bf16_rne(x - hf);  // exact residual
}

// ---- W prep: layout [o_tile(16)][ks(8)][hilo(2)][lane(64)][4 u32] = 256 KB ----
// A-fragment (mfma_f32_16x16x32_bf16): lane l holds A[m=l&15][k=(l>>4)*8+j], j=0..7
// Block stride per (o_tile,ks) = 512 u32; hilo stride = 256 u32.
__global__ __launch_bounds__(256) void prep_w_kernel(const float* __restrict__ W,
                                                     u32* __restrict__ wf) {
  int gid  = blockIdx.x * 256 + threadIdx.x;  // 0..8191
  int lane = gid & 63;
  int ks   = (gid >> 6) & 7;
  int ot   = gid >> 9;
  int row  = ot * 16 + (lane & 15);
  int col  = ks * 32 + ((lane >> 4) & 3) * 8;
  const float* src = W + row * 256 + col;
  u32 hi[4], lo[4];
#pragma unroll
  for (int p = 0; p < 4; ++p) {
    u32 h0, l0, h1, l1;
    split2(src[2 * p], h0, l0);
    split2(src[2 * p + 1], h1, l1);
    hi[p] = (h1 << 16) | h0;  // bf16 pair: elem 2p low half, 2p+1 high half
    lo[p] = (l1 << 16) | l0;
  }
  u32 base = (u32)(ot * 8 + ks) * 512 + (u32)lane * 4;
  u32x4 vh = { hi[0], hi[1], hi[2], hi[3] };
  u32x4 vl = { lo[0], lo[1], lo[2], lo[3] };
  *(u32x4*)(wf + base)       = vh;
  *(u32x4*)(wf + base + 256) = vl;
}

// ---- main kernel: one wg = 16 edges; GEMM M=256 (64/wave), N=48, K=256 ----
__global__ __launch_bounds__(256, 3) void edge_mfma_kernel(const float* __restrict__ x,
                                                           const u32* __restrict__ wf,
                                                           float* __restrict__ out,
                                                           int nedges) {
  // xs: B tile [n(48)][k(256)] packed u32 = (hi16(x)<<16)|hi16(lo), XOR-swizzled:
  // u32 index = n*256 + (((k>>2) ^ (n&7)) << 2) + (k&3).  48 KB.
  __shared__ u32 xs[48 * 256];
  const int tid  = threadIdx.x;
  const int lane = tid & 63;
  const int wave = tid >> 6;
  const int kgrp = (lane >> 4) & 3;
  const long e0  = (long)blockIdx.x * EDGES_PER_WG;

  // ---------- stage: wave-per-edge, 4 passes; lane l owns floats [12l,12l+12) ----------
  // Decode is div-free: I = 4l + q/3 (q compile-time), i = q%3.
#pragma unroll
  for (int p = 0; p < 4; ++p) {
    const int el_ = p * 4 + wave;          // WG pass p loads edges 4p..4p+3: contiguous 12KB
    const long e = e0 + el_;
    if (e < (long)nedges) {
      const float* src = x + e * 768 + lane * 12;   // 48B-aligned
      f32x4 v0 = *(const f32x4*)(src);
      f32x4 v1 = *(const f32x4*)(src + 4);
      f32x4 v2 = *(const f32x4*)(src + 8);
      float f[12] = { v0.x, v0.y, v0.z, v0.w, v1.x, v1.y, v1.z, v1.w,
                      v2.x, v2.y, v2.z, v2.w };
#pragma unroll
      for (int i = 0; i < 3; ++i) {
        const int n = el_ * 3 + i;
        u32x4 w4;
#pragma unroll
        for (int c = 0; c < 4; ++c) {                 // k = 4*lane + c
          const float xv = f[c * 3 + i];
          const u32 u  = __builtin_bit_cast(u32, xv);
          const u32 hb = u & 0xFFFF0000u;             // hi = truncated bf16 (exact bits)
          const float lo = xv - __builtin_bit_cast(float, hb);  // exact residual
          const u32 ul = __builtin_bit_cast(u32, lo);
          w4[c] = __builtin_amdgcn_perm(u, ul, 0x07060302u);    // (u.hi16<<16)|ul.hi16
        }
        *(u32x4*)(xs + n * 256 + ((lane ^ (n & 7)) << 2)) = w4;  // slot=(k>>2)^(n&7)=lane^sn
      }
    }
  }
  __syncthreads();

  // column decode: n -> (e_local, i)
  int el[3], il[3];
#pragma unroll
  for (int nt = 0; nt < 3; ++nt) {
    const int n = nt * 16 + (lane & 15);
    el[nt] = n / 3;
    il[nt] = n - el[nt] * 3;
  }

  f32x4 acc[4][3];
#pragma unroll
  for (int a = 0; a < 4; ++a)
#pragma unroll
    for (int b = 0; b < 3; ++b)
      acc[a][b] = (f32x4){0.f, 0.f, 0.f, 0.f};

#pragma unroll 1
  for (int kc = 0; kc < 4; ++kc) {          // K chunks of 64
#pragma unroll
    for (int ks = 0; ks < 2; ++ks) {        // 32-k sub-chunks
      // ---- B fragments for this (kc,ks): hi/lo, 24 VGPRs live ----
      u32x4 bh[3], bl[3];
#pragma unroll
      for (int nt = 0; nt < 3; ++nt) {
        const int n  = nt * 16 + (lane & 15);
        const int sn = n & 7;                          // == lane & 7
        const u32* rowp = xs + n * 256;
        const int g = kc * 16 + ks * 8 + kgrp * 2;     // 16B-granule index (pre-swizzle)
        u32x4 ua = *(const u32x4*)(rowp + ((g ^ sn) << 2));
        u32x4 ub = *(const u32x4*)(rowp + (((g + 1) ^ sn) << 2));
        u32 u[8] = { ua.x, ua.y, ua.z, ua.w, ub.x, ub.y, ub.z, ub.w };
        u32 ph[4], pl[4];
#pragma unroll
        for (int p = 0; p < 4; ++p) {
          ph[p] = __builtin_amdgcn_perm(u[2 * p + 1], u[2 * p], 0x07060302u); // hi16 pair
          pl[p] = __builtin_amdgcn_perm(u[2 * p + 1], u[2 * p], 0x05040100u); // lo16 pair
        }
        bh[nt] = (u32x4){ ph[0], ph[1], ph[2], ph[3] };
        bl[nt] = (u32x4){ pl[0], pl[1], pl[2], pl[3] };
      }
      // ---- A fragments from pre-arranged W (L2-resident, coalesced) ----
#pragma unroll
      for (int ot = 0; ot < 4; ++ot) {
        const u32* ap = wf + (u32)(((wave * 4 + ot) * 8 + kc * 2 + ks) * 512)
                           + (u32)lane * 4;
        u32x4 ahi = *(const u32x4*)(ap);
        u32x4 alo = *(const u32x4*)(ap + 256);
        bf16x8 Ah = __builtin_bit_cast(bf16x8, ahi);
        bf16x8 Al = __builtin_bit_cast(bf16x8, alo);
        // hi*hi + hi*lo + lo*hi; round-robin over 3 accumulators
#pragma unroll
        for (int nt = 0; nt < 3; ++nt)
          acc[ot][nt] = __builtin_amdgcn_mfma_f32_16x16x32_bf16(
              Ah, __builtin_bit_cast(bf16x8, bh[nt]), acc[ot][nt], 0, 0, 0);
#pragma unroll
        for (int nt = 0; nt < 3; ++nt)
          acc[ot][nt] = __builtin_amdgcn_mfma_f32_16x16x32_bf16(
              Ah, __builtin_bit_cast(bf16x8, bl[nt]), acc[ot][nt], 0, 0, 0);
#pragma unroll
        for (int nt = 0; nt < 3; ++nt)
          acc[ot][nt] = __builtin_amdgcn_mfma_f32_16x16x32_bf16(
              Al, __builtin_bit_cast(bf16x8, bh[nt]), acc[ot][nt], 0, 0, 0);
      }
    }
  }

  // ---------- epilogue: C/D layout col(lane&15)=n, row=(lane>>4)*4+reg=m ----------
#pragma unroll
  for (int ot = 0; ot < 4; ++ot) {
    const int obase = wave * 64 + ot * 16 + kgrp * 4;
#pragma unroll
    for (int nt = 0; nt < 3; ++nt) {
      const long e = e0 + el[nt];
      if (e < nedges) {
        float* op = out + e * 768 + il[nt];
#pragma unroll
        for (int r = 0; r < 4; ++r)
          op[(long)(obase + r) * 3] = acc[ot][nt][r];
      }
    }
  }
}

// ---- emergency fallback (only if ws_size < 256 KB): plain fp32, compute-bound ----
__global__ __launch_bounds__(256) void edge_naive_kernel(const float* __restrict__ x,
                                                         const float* __restrict__ W,
                                                         float* __restrict__ out,
                                                         int nedges) {
  __shared__ float xe[768];
  const long e = blockIdx.x;
  if (e >= nedges) return;
  const float* xp = x + e * 768;
  for (int t = threadIdx.x; t < 768; t += 256) xe[t] = xp[t];
  __syncthreads();
  const int O = threadIdx.x;
  const float* wrow = W + O * 256;
  float s0 = 0.f, s1 = 0.f, s2 = 0.f;
#pragma unroll 4
  for (int I = 0; I < 256; I += 4) {
    f32x4 w = *(const f32x4*)(wrow + I);
#pragma unroll
    for (int q = 0; q < 4; ++q) {
      const float wv = w[q];
      s0 += wv * xe[(I + q) * 3 + 0];
      s1 += wv * xe[(I + q) * 3 + 1];
      s2 += wv * xe[(I + q) * 3 + 2];
    }
  }
  float* op = out + e * 768 + (long)O * 3;
  op[0] = s0; op[1] = s1; op[2] = s2;
}

extern "C" void kernel_launch(void* const* d_in, const int* in_sizes, int n_in,
                              void* d_out, int out_size, void* d_ws, size_t ws_size,
                              hipStream_t stream) {
  const float* x = (const float*)d_in[0];
  const float* W = (const float*)d_in[1];
  float* out     = (float*)d_out;
  const int nedges = in_sizes[0] / 768;  // DIM_IN(256) * SPATIAL(3)

  if (ws_size >= 262144) {
    u32* wf = (u32*)d_ws;
    prep_w_kernel<<<32, 256, 0, stream>>>(W, wf);
    const int ntiles = (nedges + EDGES_PER_WG - 1) / EDGES_PER_WG;
    edge_mfma_kernel<<<ntiles, 256, 0, stream>>>(x, wf, out, nedges);
  } else {
    edge_naive_kernel<<<nedges, 256, 0, stream>>>(x, W, out, nedges);
  }
}

// Round 4
// 533.810 us; speedup vs baseline: 1.1642x; 1.1642x over previous
//
#include <hip/hip_runtime.h>
#include <cstdint>

typedef uint32_t u32;
typedef __attribute__((ext_vector_type(4))) float f32x4;
typedef __attribute__((ext_vector_type(4))) u32   u32x4;
typedef __attribute__((ext_vector_type(8))) short bf16x8;

#define EDGES_PER_WG 16
#define OSTRIDE 772  // epilogue LDS row stride (dwords); 768+4 -> conflict-free banks

// ---- bf16 RNE helpers ----
__device__ __forceinline__ u32 bf16_rne(float x) {
  u32 u = __builtin_bit_cast(u32, x);
  return (u + 0x7FFFu + ((u >> 16) & 1u)) >> 16;
}
__device__ __forceinline__ void split2(float x, u32 &h, u32 &l) {
  h = bf16_rne(x);
  float hf = __builtin_bit_cast(float, h << 16);
  l = bf16_rne(x - hf);  // exact residual, then RNE
}

// ---- W prep: layout [o_tile(16)][s(8)][hilo(2)][lane(64)][4 u32] = 256 KB ----
// A-fragment (mfma_f32_16x16x32_bf16): lane l holds A[m=l&15][k=(l>>4)*8+j], j=0..7
// Block stride per (o_tile,s) = 512 u32; hilo stride = 256 u32.
__global__ __launch_bounds__(256) void prep_w_kernel(const float* __restrict__ W,
                                                     u32* __restrict__ wf) {
  int gid  = blockIdx.x * 256 + threadIdx.x;  // 0..8191
  int lane = gid & 63;
  int ks   = (gid >> 6) & 7;
  int ot   = gid >> 9;
  int row  = ot * 16 + (lane & 15);
  int col  = ks * 32 + ((lane >> 4) & 3) * 8;
  const float* src = W + row * 256 + col;
  u32 hi[4], lo[4];
#pragma unroll
  for (int p = 0; p < 4; ++p) {
    u32 h0, l0, h1, l1;
    split2(src[2 * p], h0, l0);
    split2(src[2 * p + 1], h1, l1);
    hi[p] = (h1 << 16) | h0;
    lo[p] = (l1 << 16) | l0;
  }
  u32 base = (u32)(ot * 8 + ks) * 512 + (u32)lane * 4;
  u32x4 vh = { hi[0], hi[1], hi[2], hi[3] };
  u32x4 vl = { lo[0], lo[1], lo[2], lo[3] };
  *(u32x4*)(wf + base)       = vh;
  *(u32x4*)(wf + base + 256) = vl;
}

// ---- main kernel: one wg = 16 edges; GEMM M=256 (64/wave), N=48, K=256 ----
__global__ __launch_bounds__(256, 3) void edge_mfma_kernel(const float* __restrict__ x,
                                                           const u32* __restrict__ wf,
                                                           float* __restrict__ out,
                                                           int nedges) {
  // Phase 1 (B tile): xs[n(48)][k(256)] packed u32 = (bf16hi<<16)|bf16lo, swizzled:
  //   u32 index = n*256 + (((k>>2) ^ (n&7)) << 2) + (k&3).   12288 u32.
  // Phase 2 (epilogue): float tile [16][OSTRIDE].  max 12347 u32.
  __shared__ u32 xs[12352];  // 49408 B -> still 3 WG/CU
  const int tid  = threadIdx.x;
  const int lane = tid & 63;
  const int wave = tid >> 6;
  const int kgrp = (lane >> 4) & 3;
  const int sn   = lane & 7;
  const long e0  = (long)blockIdx.x * EDGES_PER_WG;

  // ---------- stage: wave-per-edge, 4 passes; lane l owns floats [12l,12l+12) ----------
#pragma unroll
  for (int p = 0; p < 4; ++p) {
    const int eloc = p * 4 + wave;
    const long e = e0 + eloc;
    if (e < (long)nedges) {
      const float* src = x + e * 768 + lane * 12;
      f32x4 v0 = *(const f32x4*)(src);
      f32x4 v1 = *(const f32x4*)(src + 4);
      f32x4 v2 = *(const f32x4*)(src + 8);
      float f[12] = { v0.x, v0.y, v0.z, v0.w, v1.x, v1.y, v1.z, v1.w,
                      v2.x, v2.y, v2.z, v2.w };
#pragma unroll
      for (int i = 0; i < 3; ++i) {
        const int n = eloc * 3 + i;
        u32x4 w4;
#pragma unroll
        for (int c = 0; c < 4; ++c) {                 // k = 4*lane + c
          const float xv = f[c * 3 + i];
          const u32 u  = __builtin_bit_cast(u32, xv);
          const u32 hb = u & 0xFFFF0000u;             // hi = trunc bf16 (exact bits)
          const float lo = xv - __builtin_bit_cast(float, hb);  // exact residual
          u32 ul = __builtin_bit_cast(u32, lo);
          ul += 0x7FFFu + ((ul >> 16) & 1u);          // RNE round of lo to bf16
          w4[c] = __builtin_amdgcn_perm(u, ul, 0x07060302u);  // (hi16(u)<<16)|hi16(ul)
        }
        *(u32x4*)(xs + n * 256 + ((lane ^ (n & 7)) << 2)) = w4;
      }
    }
  }
  __syncthreads();

  f32x4 acc[4][3];
#pragma unroll
  for (int a = 0; a < 4; ++a)
#pragma unroll
    for (int b = 0; b < 3; ++b)
      acc[a][b] = (f32x4){0.f, 0.f, 0.f, 0.f};

  // ---------- software-pipelined K loop: 8 stages of K=32 ----------
  u32x4 Bh[2][3], Bl[2][3], Ah[2][4];

  auto loadB = [&](int s, int b) {
#pragma unroll
    for (int nt = 0; nt < 3; ++nt) {
      const u32* rowp = xs + (nt * 16 + (lane & 15)) * 256;
      const int g = s * 8 + kgrp * 2;
      u32x4 ua = *(const u32x4*)(rowp + ((g ^ sn) << 2));
      u32x4 ub = *(const u32x4*)(rowp + (((g + 1) ^ sn) << 2));
      u32 uu[8] = { ua.x, ua.y, ua.z, ua.w, ub.x, ub.y, ub.z, ub.w };
      u32 ph[4], pl[4];
#pragma unroll
      for (int p = 0; p < 4; ++p) {
        ph[p] = __builtin_amdgcn_perm(uu[2 * p + 1], uu[2 * p], 0x07060302u);
        pl[p] = __builtin_amdgcn_perm(uu[2 * p + 1], uu[2 * p], 0x05040100u);
      }
      Bh[b][nt] = (u32x4){ ph[0], ph[1], ph[2], ph[3] };
      Bl[b][nt] = (u32x4){ pl[0], pl[1], pl[2], pl[3] };
    }
  };
  auto loadAh = [&](int s, int b) {
#pragma unroll
    for (int ot = 0; ot < 4; ++ot)
      Ah[b][ot] = *(const u32x4*)(wf + (u32)(((wave * 4 + ot) * 8 + s) * 512)
                                     + (u32)lane * 4);
  };

  loadB(0, 0);
  loadAh(0, 0);

#pragma unroll
  for (int s = 0; s < 8; ++s) {
    const int b = s & 1;
    // Al for this stage: first consumed 24 MFMAs from now (covers L2 latency)
    u32x4 Alv[4];
#pragma unroll
    for (int ot = 0; ot < 4; ++ot)
      Alv[ot] = *(const u32x4*)(wf + (u32)(((wave * 4 + ot) * 8 + s) * 512 + 256)
                                   + (u32)lane * 4);
    if (s < 7) { loadB(s + 1, b ^ 1); loadAh(s + 1, b ^ 1); }
    // product-major MFMA blocks: acc reuse distance = 12
#pragma unroll
    for (int ot = 0; ot < 4; ++ot) {
      bf16x8 ah = __builtin_bit_cast(bf16x8, Ah[b][ot]);
#pragma unroll
      for (int nt = 0; nt < 3; ++nt)
        acc[ot][nt] = __builtin_amdgcn_mfma_f32_16x16x32_bf16(
            ah, __builtin_bit_cast(bf16x8, Bh[b][nt]), acc[ot][nt], 0, 0, 0);
    }
#pragma unroll
    for (int ot = 0; ot < 4; ++ot) {
      bf16x8 ah = __builtin_bit_cast(bf16x8, Ah[b][ot]);
#pragma unroll
      for (int nt = 0; nt < 3; ++nt)
        acc[ot][nt] = __builtin_amdgcn_mfma_f32_16x16x32_bf16(
            ah, __builtin_bit_cast(bf16x8, Bl[b][nt]), acc[ot][nt], 0, 0, 0);
    }
#pragma unroll
    for (int ot = 0; ot < 4; ++ot) {
      bf16x8 al = __builtin_bit_cast(bf16x8, Alv[ot]);
#pragma unroll
      for (int nt = 0; nt < 3; ++nt)
        acc[ot][nt] = __builtin_amdgcn_mfma_f32_16x16x32_bf16(
            al, __builtin_bit_cast(bf16x8, Bh[b][nt]), acc[ot][nt], 0, 0, 0);
    }
  }

  // ---------- epilogue: bounce through LDS for coalesced dwordx4 stores ----------
  __syncthreads();               // all waves done reading B tile
  float* os = (float*)xs;        // [16][OSTRIDE] floats
#pragma unroll
  for (int ot = 0; ot < 4; ++ot) {
    const int obase = wave * 64 + ot * 16 + kgrp * 4;
#pragma unroll
    for (int nt = 0; nt < 3; ++nt) {
      const int n  = nt * 16 + (lane & 15);
      const int el = n / 3;
      const int il = n - el * 3;
      float* rowp = os + el * OSTRIDE + il;
#pragma unroll
      for (int r = 0; r < 4; ++r)
        rowp[(obase + r) * 3] = acc[ot][nt][r];   // C/D: col=lane&15(=n), row=m
    }
  }
  __syncthreads();
#pragma unroll
  for (int p = 0; p < 4; ++p) {
    const int eloc = p * 4 + wave;
    const long e = e0 + eloc;
    if (e < (long)nedges) {
      const float* src = os + eloc * OSTRIDE;
      float* dst = out + e * 768;
#pragma unroll
      for (int r = 0; r < 3; ++r) {
        f32x4 v = *(const f32x4*)(src + r * 256 + lane * 4);
        *(f32x4*)(dst + r * 256 + lane * 4) = v;
      }
    }
  }
}

// ---- emergency fallback (only if ws_size < 256 KB): plain fp32, compute-bound ----
__global__ __launch_bounds__(256) void edge_naive_kernel(const float* __restrict__ x,
                                                         const float* __restrict__ W,
                                                         float* __restrict__ out,
                                                         int nedges) {
  __shared__ float xe[768];
  const long e = blockIdx.x;
  if (e >= nedges) return;
  const float* xp = x + e * 768;
  for (int t = threadIdx.x; t < 768; t += 256) xe[t] = xp[t];
  __syncthreads();
  const int O = threadIdx.x;
  const float* wrow = W + O * 256;
  float s0 = 0.f, s1 = 0.f, s2 = 0.f;
#pragma unroll 4
  for (int I = 0; I < 256; I += 4) {
    f32x4 w = *(const f32x4*)(wrow + I);
#pragma unroll
    for (int q = 0; q < 4; ++q) {
      const float wv = w[q];
      s0 += wv * xe[(I + q) * 3 + 0];
      s1 += wv * xe[(I + q) * 3 + 1];
      s2 += wv * xe[(I + q) * 3 + 2];
    }
  }
  float* op = out + e * 768 + (long)O * 3;
  op[0] = s0; op[1] = s1; op[2] = s2;
}

extern "C" void kernel_launch(void* const* d_in, const int* in_sizes, int n_in,
                              void* d_out, int out_size, void* d_ws, size_t ws_size,
                              hipStream_t stream) {
  const float* x = (const float*)d_in[0];
  const float* W = (const float*)d_in[1];
  float* out     = (float*)d_out;
  const int nedges = in_sizes[0] / 768;  // DIM_IN(256) * SPATIAL(3)

  if (ws_size >= 262144) {
    u32* wf = (u32*)d_ws;
    prep_w_kernel<<<32, 256, 0, stream>>>(W, wf);
    const int ntiles = (nedges + EDGES_PER_WG - 1) / EDGES_PER_WG;
    edge_mfma_kernel<<<ntiles, 256, 0, stream>>>(x, wf, out, nedges);
  } else {
    edge_naive_kernel<<<nedges, 256, 0, stream>>>(x, W, out, nedges);
  }
}